// Round 8
// baseline (1152.414 us; speedup 1.0000x reference)
//
#include <hip/hip_runtime.h>

typedef unsigned short ushort_t;
typedef __attribute__((ext_vector_type(8))) short short8;
typedef __attribute__((ext_vector_type(4))) float floatx4;
typedef __attribute__((ext_vector_type(4))) unsigned int uintx4;

#define BSZ   512
#define UNITS 256
#define IMG   64
#define STEPS 10
#define GATES 1024
// folded ext layout per batch row: [x_hat 4096 | h_dec 256 | h_enc 256]
#define KENC  4608
#define NBLK  256   // persistent grid: one block per CU
#define BK 32
#define FLAG_STRIDE 32                       // 128 B per block flag slot (grid bar)

__device__ inline float b2f(ushort_t u) {
  union { float f; unsigned int i; } v; v.i = ((unsigned int)u) << 16; return v.f;
}
__device__ inline ushort_t f2b(float f) {
  unsigned int u = __float_as_uint(f);
  u += 0x7fffu + ((u >> 16) & 1u);          // round-to-nearest-even
  return (ushort_t)(u >> 16);
}
__device__ inline float sigm(float x) { return 1.f / (1.f + __expf(-x)); }

// Weights: cached global->LDS DMA (aux=0 — proven path).
#define GLL(g, l) __builtin_amdgcn_global_load_lds(                      \
    (const __attribute__((address_space(1))) void*)(g),                  \
    (__attribute__((address_space(3))) void*)(l), 16, 0, 0)

// Coherent scalar ops (relaxed agent atomics -> sc0 sc1) — the proven
// cross-block activation path.
#define CLOADF(p)    __hip_atomic_load((p), __ATOMIC_RELAXED, __HIP_MEMORY_SCOPE_AGENT)
#define CSTOREF(p,v) __hip_atomic_store((p), (v), __ATOMIC_RELAXED, __HIP_MEMORY_SCOPE_AGENT)
#define CSTOREU(p,v) __hip_atomic_store((p), (ushort_t)(v), __ATOMIC_RELAXED, __HIP_MEMORY_SCOPE_AGENT)

// 16B coherent global load (result NOT ready until s_waitcnt vmcnt).
__device__ inline uintx4 cload16(const ushort_t* p) {
  uintx4 r;
  asm volatile("global_load_dwordx4 %0, %1, off sc0 sc1" : "=v"(r) : "v"(p));
  return r;
}
__device__ inline void waitvm0() {
  asm volatile("s_waitcnt vmcnt(0)" ::: "memory");
}
__device__ inline unsigned ldsaddr(const ushort_t* p) {
  return (unsigned)(unsigned long long)(const __attribute__((address_space(3))) void*)p;
}
__device__ inline void dsw16(unsigned off, uintx4 v) {
  asm volatile("ds_write_b128 %0, %1" :: "v"(off), "v"(v));
}

// ---------------------------------------------------------------------------
// Grid barrier (R2/R3/R6/R7-proven).
// ---------------------------------------------------------------------------
__device__ inline void gridbar(unsigned* bar, unsigned id) {
  __syncthreads();
  const int b = blockIdx.x, t = threadIdx.x;
  unsigned* gen = bar + NBLK * FLAG_STRIDE;
  if (b == 0) {
    if (t > 0 && t < NBLK) {
      while (__hip_atomic_load(bar + t * FLAG_STRIDE, __ATOMIC_RELAXED,
                               __HIP_MEMORY_SCOPE_AGENT) < id)
        __builtin_amdgcn_s_sleep(1);
    }
    __syncthreads();
    if (t == 0)
      __hip_atomic_store(gen, id, __ATOMIC_RELAXED, __HIP_MEMORY_SCOPE_AGENT);
  } else if (t == 0) {
    __hip_atomic_store(bar + b * FLAG_STRIDE, id, __ATOMIC_RELAXED,
                       __HIP_MEMORY_SCOPE_AGENT);
    while (__hip_atomic_load(gen, __ATOMIC_RELAXED,
                             __HIP_MEMORY_SCOPE_AGENT) < id)
      __builtin_amdgcn_s_sleep(1);
  }
  __syncthreads();
}

// ---------------------------------------------------------------------------
// Fold patch weights into per-pixel weights + transpose (hi only).
// ---------------------------------------------------------------------------
__global__ __launch_bounds__(256) void k_prep_pix(const float* __restrict__ ek,
                                                  ushort_t* __restrict__ ohi) {
  __shared__ float T[64][68];
  int t = threadIdx.x;
  int pix0 = blockIdx.x * 64, n0 = blockIdx.y * 64;
  int r = t >> 2, seg = t & 3;
  int pix = pix0 + r;
  int ri = pix >> 6, ci = pix & 63;
  float4 acc4[4];
#pragma unroll
  for (int j = 0; j < 4; ++j) acc4[j] = float4{0.f, 0.f, 0.f, 0.f};
#pragma unroll
  for (int di = 0; di < 3; ++di) {
    int ii = ri - di;
    if (ii < 0 || (ii & 1)) continue;
    int oi = ii >> 1;  if (oi >= 32) continue;
#pragma unroll
    for (int dj = 0; dj < 3; ++dj) {
      int jj = ci - dj;
      if (jj < 0 || (jj & 1)) continue;
      int oj = jj >> 1;  if (oj >= 32) continue;
      const float* row = ek + (size_t)((oi * 32 + oj) * 9 + di * 3 + dj) * GATES
                         + n0 + seg * 16;
#pragma unroll
      for (int j = 0; j < 4; ++j) {
        float4 v = *(const float4*)(row + j * 4);
        acc4[j].x += v.x; acc4[j].y += v.y; acc4[j].z += v.z; acc4[j].w += v.w;
      }
    }
  }
#pragma unroll
  for (int j = 0; j < 4; ++j) *(float4*)&T[r][seg * 16 + j * 4] = acc4[j];
  __syncthreads();
  ushort_t thi[16];
#pragma unroll
  for (int j = 0; j < 16; ++j) thi[j] = f2b(T[seg * 16 + j][r]);
  size_t off = (size_t)(n0 + r) * KENC + pix0 + seg * 16;
  *(uint4*)(ohi + off)     = *(const uint4*)&thi[0];
  *(uint4*)(ohi + off + 8) = *(const uint4*)&thi[8];
}

// ---------------------------------------------------------------------------
// Multi-job transpose prep (one dispatch). Also zeroes the grid-barrier words.
// ---------------------------------------------------------------------------
__global__ __launch_bounds__(256) void k_prep_multi(
    const float* __restrict__ ek, const float* __restrict__ er,
    const float* __restrict__ dk, const float* __restrict__ dr,
    const float* __restrict__ Wdec,
    ushort_t* __restrict__ Wet_hi,
    ushort_t* __restrict__ Wdt_hi, ushort_t* __restrict__ Wdt_lo,
    ushort_t* __restrict__ Wct_hi, ushort_t* __restrict__ Wct_lo,
    unsigned* __restrict__ bar) {
  __shared__ float T[64][68];
  int t = threadIdx.x;
  int z = blockIdx.z;
  int k0 = blockIdx.x * 64, n0 = blockIdx.y * 64;
  int r = t >> 2, seg = t & 3;
  if (z == 0) {
    int fid = (blockIdx.y * 4 + blockIdx.x) * 256 + t;
    if (fid <= NBLK * FLAG_STRIDE) bar[fid] = 0u;   // flags + gen
  }

  const float *s0, *s1 = nullptr;
  ushort_t *ohi, *olo = nullptr;
  int src_ld, out_ld, koff;
  if (z == 0) { s0 = ek + (size_t)9216 * GATES; s1 = ek + (size_t)9472 * GATES;
                src_ld = GATES; ohi = Wet_hi; out_ld = KENC; koff = 4096; }
  else if (z == 1) { s0 = er; src_ld = GATES; ohi = Wet_hi; out_ld = KENC; koff = 4352; }
  else if (z == 2) { s0 = dk; src_ld = GATES; ohi = Wdt_hi; olo = Wdt_lo; out_ld = 512; koff = 0; }
  else if (z == 3) { s0 = dr; src_ld = GATES; ohi = Wdt_hi; olo = Wdt_lo; out_ld = 512; koff = 256; }
  else { s0 = Wdec; src_ld = 4096; ohi = Wct_hi; olo = Wct_lo; out_ld = 256; koff = 0;
         n0 += (z - 4) * 1024; }

  const float* src = s0 + (size_t)(k0 + r) * src_ld + n0 + seg * 16;
  const float* src2 = s1 ? (s1 + (size_t)(k0 + r) * src_ld + n0 + seg * 16) : nullptr;
#pragma unroll
  for (int j = 0; j < 4; ++j) {
    float4 v = *(const float4*)(src + j * 4);
    if (src2) {
      float4 w = *(const float4*)(src2 + j * 4);
      v.x += w.x; v.y += w.y; v.z += w.z; v.w += w.w;
    }
    *(float4*)&T[r][seg * 16 + j * 4] = v;
  }
  __syncthreads();
  ushort_t thi[16], tlo[16];
#pragma unroll
  for (int j = 0; j < 16; ++j) {
    float v = T[seg * 16 + j][r];
    ushort_t h = f2b(v);
    thi[j] = h;
    tlo[j] = f2b(v - b2f(h));
  }
  size_t off = (size_t)(n0 + r) * out_ld + koff + k0 + seg * 16;
  *(uint4*)(ohi + off)     = *(const uint4*)&thi[0];
  *(uint4*)(ohi + off + 8) = *(const uint4*)&thi[8];
  if (olo) {
    *(uint4*)(olo + off)     = *(const uint4*)&tlo[0];
    *(uint4*)(olo + off + 8) = *(const uint4*)&tlo[8];
  }
}

// ---------------------------------------------------------------------------
// Persistent kernel: 10 steps, 4 phases/step, all 256 blocks busy each phase.
//  E : enc GEMM, M=16 x N=512(2 u-regions) x z=4, 36 kt, partials -> zep
//  E2: LSTM reduce(4, vectorized loads) + attention + glimpse (2 rows/block)
//  D : dec GEMM full-K 3-product, M=16 x N=128 (32m x 8u), fused LSTM epilogue
//  C : canvas GEMM + fused x_hat, M=32 x N=256 (16m x 16n)
// LDS union 72 KiB (2 blocks/CU: 144 <= 160 KiB).
// ---------------------------------------------------------------------------
__global__ __launch_bounds__(512, 2) void k_persist(
    const float* __restrict__ x,
    const float* __restrict__ ebias, const float* __restrict__ dbias,
    const float* __restrict__ Wenc, const float* __restrict__ benc,
    const float* __restrict__ bdec,
    float* __restrict__ canvas, float* __restrict__ c_enc, float* __restrict__ c_dec,
    float* __restrict__ zep,
    ushort_t* __restrict__ ehi, ushort_t* __restrict__ dhi, ushort_t* __restrict__ dlo,
    const ushort_t* __restrict__ Wet_hi,
    const ushort_t* __restrict__ Wdt_hi, const ushort_t* __restrict__ Wdt_lo,
    const ushort_t* __restrict__ Wct_hi, const ushort_t* __restrict__ Wct_lo,
    unsigned* bar) {
  __shared__ __align__(16) ushort_t smem[36864];   // 72 KiB union
  const int b = blockIdx.x, t = threadIdx.x;
  const int lane = t & 63, w = t >> 6;
  const int q = lane >> 4, c16 = lane & 15;
  const int qs = (q ^ ((c16 >> 1) & 3)) * 8;       // swizzled k-seg read offset
  const int half = t >> 8, u8 = t & 255;
  const int rrow = b * 2 + half;
  unsigned barid = 0;

  // ---- preamble: zero state (by OWNER block) + step-0 x_hat --------------
  {
    // canvas: C-owner (bm=b>>4: 32 rows, bn=b&15: 256 cols)
    const int cm0 = (b >> 4) * 32, cn0 = (b & 15) * 64;   // col base in float4
    float4* cv4 = (float4*)canvas;
    const float4 z4 = float4{0.f, 0.f, 0.f, 0.f};
#pragma unroll
    for (int j = 0; j < 4; ++j) {
      int idx = j * 512 + t;                 // 2048 float4 = 32 rows x 64
      cv4[(size_t)(cm0 + (idx >> 6)) * 1024 + cn0 + (idx & 63)] = z4;
    }
    // c_enc: E2-owner (block b owns rows b*2, b*2+1)
    c_enc[rrow * UNITS + u8] = 0.f;
    // c_dec: D-owner (bm=b&31 rows, bu=b>>5 units)
    c_dec[((b & 31) * 16 + (t >> 5)) * UNITS + (b >> 5) * 32 + (t & 31)] = 0.f;
    // sc0sc1 state slots + step-0 x_hat (sigmoid(0)=0.5)
    CSTOREU(ehi + (size_t)rrow * KENC + 4096 + u8, 0);
    CSTOREU(ehi + (size_t)rrow * KENC + 4352 + u8, 0);
    CSTOREU(dhi + (size_t)rrow * 512 + u8, 0);
    CSTOREU(dhi + (size_t)rrow * 512 + 256 + u8, 0);
    CSTOREU(dlo + (size_t)rrow * 512 + u8, 0);
    CSTOREU(dlo + (size_t)rrow * 512 + 256 + u8, 0);
    for (int pix = u8; pix < 4096; pix += 256)
      CSTOREU(ehi + (size_t)rrow * KENC + pix,
              f2b(x[(size_t)rrow * 4096 + pix] - 0.5f));
  }
  gridbar(bar, ++barid);

  for (int s = 0; s < STEPS; ++s) {
    // ===== phase E: enc GEMM, M=16 N=512 z=4 (32m x 2u x 4z = 256) ==========
    // LDS/buf: A[16x32]@0 (512), B[512x32]@512 (16384) -> 16896; dbuf x2.
    {
      const int bm = b & 31, bu = (b >> 5) & 1, bz = b >> 6;
      const int m0 = bm * 16, kstart = bz * 1152;          // 36 kt
      const int sseg = (t & 3) ^ ((t >> 3) & 3);
      const ushort_t* pA = ehi + (size_t)(m0 + (t >> 2)) * KENC + kstart + sseg * 8;
      const int br = t >> 2;                               // 0..127
      const ushort_t* pB[4];
#pragma unroll
      for (int c = 0; c < 4; ++c) {
        const int r0 = c * 128 + br;                       // 0..511
        const int srow = (r0 >> 7) * 256 + bu * 128 + (r0 & 127);
        pB[c] = Wet_hi + (size_t)srow * KENC + kstart + sseg * 8;
      }

      floatx4 acc[4];
#pragma unroll
      for (int j = 0; j < 4; ++j) acc[j] = floatx4{0.f, 0.f, 0.f, 0.f};

      uintx4 va;
      if (t < 64) va = cload16(pA);
#pragma unroll
      for (int c = 0; c < 4; ++c) GLL(pB[c], &smem[512 + c * 4096 + t * 8]);
      pA += BK;
#pragma unroll
      for (int c = 0; c < 4; ++c) pB[c] += BK;
      waitvm0();
      if (t < 64) dsw16(ldsaddr(&smem[t * 8]), va);
      __syncthreads();
      for (int kt = 0; kt < 36; ++kt) {
        const int cur = (kt & 1) * 16896, nxt = 16896 - cur;
        if (kt + 1 < 36) {
          if (t < 64) va = cload16(pA);
#pragma unroll
          for (int c = 0; c < 4; ++c) GLL(pB[c], &smem[nxt + 512 + c * 4096 + t * 8]);
          pA += BK;
#pragma unroll
          for (int c = 0; c < 4; ++c) pB[c] += BK;
        }
        short8 af = *(const short8*)&smem[cur + c16 * BK + qs];
        short8 bf[4];
#pragma unroll
        for (int j = 0; j < 4; ++j)
          bf[j] = *(const short8*)&smem[cur + 512 + (w * 64 + j * 16 + c16) * BK + qs];
#pragma unroll
        for (int j = 0; j < 4; ++j)
          acc[j] = __builtin_amdgcn_mfma_f32_16x16x32_bf16(af, bf[j], acc[j], 0, 0, 0);
        if (kt + 1 < 36) {
          waitvm0();
          if (t < 64) dsw16(ldsaddr(&smem[nxt + t * 8]), va);
        }
        __syncthreads();
      }
      // store partials: zep[row][unit][bz*4+gate]
#pragma unroll
      for (int ni = 0; ni < 4; ++ni) {
        const int col = w * 64 + ni * 16 + c16;            // 0..511
        const int g = col >> 7, uu = col & 127;
        const int unit = bu * 128 + uu;
#pragma unroll
        for (int r = 0; r < 4; ++r)
          CSTOREF(zep + (size_t)(m0 + q * 4 + r) * 4096 + unit * 16 + bz * 4 + g,
                  acc[ni][r]);
      }
    }
    gridbar(bar, ++barid);

    // ===== phase E2: LSTM reduce(4, vector loads) + attention (2 rows/blk) ==
    {
      float* shf = (float*)smem;        // [0,512): h (2 rows); [512,532): logits
      const float* rb = zep + (size_t)rrow * 4096 + u8 * 16;
      uintx4 v0 = cload16((const ushort_t*)(rb));
      uintx4 v1 = cload16((const ushort_t*)(rb + 4));
      uintx4 v2 = cload16((const ushort_t*)(rb + 8));
      uintx4 v3 = cload16((const ushort_t*)(rb + 12));
      waitvm0();
      float zi = ebias[u8]       + __uint_as_float(v0[0]) + __uint_as_float(v1[0])
                                 + __uint_as_float(v2[0]) + __uint_as_float(v3[0]);
      float zf = ebias[u8 + 256] + __uint_as_float(v0[1]) + __uint_as_float(v1[1])
                                 + __uint_as_float(v2[1]) + __uint_as_float(v3[1]);
      float zg = ebias[u8 + 512] + __uint_as_float(v0[2]) + __uint_as_float(v1[2])
                                 + __uint_as_float(v2[2]) + __uint_as_float(v3[2]);
      float zo = ebias[u8 + 768] + __uint_as_float(v0[3]) + __uint_as_float(v1[3])
                                 + __uint_as_float(v2[3]) + __uint_as_float(v3[3]);
      float c = c_enc[rrow * UNITS + u8];
      float cn = sigm(zf) * c + sigm(zi) * tanhf(zg);
      float h = sigm(zo) * tanhf(cn);
      c_enc[rrow * UNITS + u8] = cn;
      CSTOREU(ehi + (size_t)rrow * KENC + 4352 + u8, f2b(h));
      shf[half * 256 + u8] = h;
      __syncthreads();
      if (u8 < 64) {    // waves 0 and 4: full-wave shuffle reduce per row
        float acc[10];
#pragma unroll
        for (int j = 0; j < 10; ++j) acc[j] = 0.f;
        for (int qq = 0; qq < 4; ++qq) {
          float hv = shf[half * 256 + u8 + qq * 64];
          const float* wr = Wenc + (u8 + qq * 64) * 10;
#pragma unroll
          for (int j = 0; j < 10; ++j) acc[j] += hv * wr[j];
        }
        for (int off = 32; off > 0; off >>= 1)
#pragma unroll
          for (int j = 0; j < 10; ++j) acc[j] += __shfl_down(acc[j], off);
        if (u8 == 0)
          for (int j = 0; j < 10; ++j) shf[512 + half * 10 + j] = acc[j] + benc[j];
      }
      __syncthreads();
      float mx = shf[512 + half * 10];
      for (int j = 1; j < 10; ++j) mx = fmaxf(mx, shf[512 + half * 10 + j]);
      float e[10], se = 0.f;
      for (int j = 0; j < 10; ++j) { e[j] = __expf(shf[512 + half * 10 + j] - mx); se += e[j]; }
      float inv = 1.f / se;
      const float* wr = Wenc + u8 * 10;
      float zzv = 0.f;
      for (int j = 0; j < 10; ++j) zzv += e[j] * inv * wr[j];
      ushort_t zh = f2b(zzv);
      CSTOREU(dhi + (size_t)rrow * 512 + u8, zh);
      CSTOREU(dlo + (size_t)rrow * 512 + u8, f2b(zzv - b2f(zh)));
    }
    gridbar(bar, ++barid);

    // ===== phase D: dec GEMM full-K, M=16 N=128 (32m x 8u = 256 blocks) =====
    // LDS/buf: Ah@0(512) Al@512(512) Bh@1024(4096) Bl@5120(4096) -> 9216; x2.
    {
      const int bm = b & 31, bu = b >> 5;
      const int m0 = bm * 16, u0 = bu * 32;
      const int ta = t & 63;
      const int sseg = (ta & 3) ^ ((ta >> 3) & 3);
      const ushort_t* pA = ((t < 64) ? dhi : dlo)
                           + (size_t)(m0 + (ta >> 2)) * 512 + sseg * 8;
      const int br = t >> 2;                               // 0..127
      const int gsrc = (br >> 5) * 256 + u0 + (br & 31);
      const int bsegD = (t & 3) ^ ((t >> 3) & 3);
      const ushort_t* pBh = Wdt_hi + (size_t)gsrc * 512 + bsegD * 8;
      const ushort_t* pBl = Wdt_lo + (size_t)gsrc * 512 + bsegD * 8;
      const int dA = ((t < 64) ? 0 : 512) + ta * 8;

      floatx4 acc = floatx4{0.f, 0.f, 0.f, 0.f};

      uintx4 va;
      if (t < 128) va = cload16(pA);
      GLL(pBh, &smem[1024 + t * 8]);
      GLL(pBl, &smem[5120 + t * 8]);
      pA += BK; pBh += BK; pBl += BK;
      waitvm0();
      if (t < 128) dsw16(ldsaddr(&smem[dA]), va);
      __syncthreads();
      for (int kt = 0; kt < 16; ++kt) {
        const int cur = (kt & 1) * 9216, nxt = 9216 - cur;
        if (kt + 1 < 16) {
          if (t < 128) va = cload16(pA);
          GLL(pBh, &smem[nxt + 1024 + t * 8]);
          GLL(pBl, &smem[nxt + 5120 + t * 8]);
          pA += BK; pBh += BK; pBl += BK;
        }
        short8 ah = *(const short8*)&smem[cur + c16 * BK + qs];
        short8 al = *(const short8*)&smem[cur + 512 + c16 * BK + qs];
        short8 bh = *(const short8*)&smem[cur + 1024 + (w * 16 + c16) * BK + qs];
        short8 bl = *(const short8*)&smem[cur + 5120 + (w * 16 + c16) * BK + qs];
        acc = __builtin_amdgcn_mfma_f32_16x16x32_bf16(ah, bh, acc, 0, 0, 0);
        acc = __builtin_amdgcn_mfma_f32_16x16x32_bf16(ah, bl, acc, 0, 0, 0);
        acc = __builtin_amdgcn_mfma_f32_16x16x32_bf16(al, bh, acc, 0, 0, 0);
        if (kt + 1 < 16) {
          waitvm0();
          if (t < 128) dsw16(ldsaddr(&smem[nxt + dA]), va);
        }
        __syncthreads();
      }
      // epilogue: acc -> LDS [16][128] -> per-unit LSTM (1 per thread)
      float* zacc = (float*)smem;
#pragma unroll
      for (int r = 0; r < 4; ++r)
        zacc[(q * 4 + r) * 128 + w * 16 + c16] = acc[r];
      __syncthreads();
      {
        const int row = t >> 5, uu = t & 31;
        const int un = u0 + uu, rg = m0 + row;
        float zi = zacc[row * 128 + uu]      + dbias[un];
        float zf = zacc[row * 128 + 32 + uu] + dbias[256 + un];
        float zg = zacc[row * 128 + 64 + uu] + dbias[512 + un];
        float zo = zacc[row * 128 + 96 + uu] + dbias[768 + un];
        float c = c_dec[rg * UNITS + un];
        float cn = sigm(zf) * c + sigm(zi) * tanhf(zg);
        float h = sigm(zo) * tanhf(cn);
        c_dec[rg * UNITS + un] = cn;
        ushort_t hh = f2b(h);
        CSTOREU(dhi + (size_t)rg * 512 + 256 + un, hh);
        CSTOREU(dlo + (size_t)rg * 512 + 256 + un, f2b(h - b2f(hh)));
        CSTOREU(ehi + (size_t)rg * KENC + 4096 + un, hh);
      }
    }
    gridbar(bar, ++barid);

    // ===== phase C: canvas GEMM + x_hat, M=32 N=256 (16m x 16n = 256) =======
    // LDS/buf: Ah@0(1024) Al@1024(1024) Bh@2048(8192) Bl@10240(8192) -> 18432; x2.
    {
      const int m0 = (b >> 4) * 32, n0 = (b & 15) * 256;
      const int wm = w >> 2, wn = w & 3;                   // 2m(16) x 4n(64)
      const int ta = t & 127;
      const int aseg = (ta & 3) ^ ((ta >> 3) & 3);
      const int bseg = (t & 3) ^ ((t >> 3) & 3);
      const ushort_t* pA = ((t < 128) ? dhi : dlo) + 256
                           + (size_t)(m0 + (ta >> 2)) * 512 + aseg * 8;
      const int br = t >> 2;                               // 0..127
      const ushort_t* pBh0 = Wct_hi + (size_t)(n0 + br) * 256 + bseg * 8;
      const ushort_t* pBh1 = Wct_hi + (size_t)(n0 + 128 + br) * 256 + bseg * 8;
      const ushort_t* pBl0 = Wct_lo + (size_t)(n0 + br) * 256 + bseg * 8;
      const ushort_t* pBl1 = Wct_lo + (size_t)(n0 + 128 + br) * 256 + bseg * 8;
      const int dA = ((t < 128) ? 0 : 1024) + ta * 8;

      floatx4 acc[4];
#pragma unroll
      for (int j = 0; j < 4; ++j) acc[j] = floatx4{0.f, 0.f, 0.f, 0.f};

      uintx4 va;
      if (t < 256) va = cload16(pA);
      GLL(pBh0, &smem[2048 + t * 8]);
      GLL(pBh1, &smem[6144 + t * 8]);
      GLL(pBl0, &smem[10240 + t * 8]);
      GLL(pBl1, &smem[14336 + t * 8]);
      pA += BK; pBh0 += BK; pBh1 += BK; pBl0 += BK; pBl1 += BK;
      waitvm0();
      if (t < 256) dsw16(ldsaddr(&smem[dA]), va);
      __syncthreads();
      for (int kt = 0; kt < 8; ++kt) {
        const int cur = (kt & 1) * 18432, nxt = 18432 - cur;
        if (kt + 1 < 8) {
          if (t < 256) va = cload16(pA);
          GLL(pBh0, &smem[nxt + 2048 + t * 8]);
          GLL(pBh1, &smem[nxt + 6144 + t * 8]);
          GLL(pBl0, &smem[nxt + 10240 + t * 8]);
          GLL(pBl1, &smem[nxt + 14336 + t * 8]);
          pA += BK; pBh0 += BK; pBh1 += BK; pBl0 += BK; pBl1 += BK;
        }
        short8 ah = *(const short8*)&smem[cur + (wm * 16 + c16) * BK + qs];
        short8 al = *(const short8*)&smem[cur + 1024 + (wm * 16 + c16) * BK + qs];
        short8 bh[4], bl[4];
#pragma unroll
        for (int j = 0; j < 4; ++j) {
          const int rb2 = (wn * 64 + j * 16 + c16) * BK + qs;
          bh[j] = *(const short8*)&smem[cur + 2048 + rb2];
          bl[j] = *(const short8*)&smem[cur + 10240 + rb2];
        }
#pragma unroll
        for (int j = 0; j < 4; ++j) {
          acc[j] = __builtin_amdgcn_mfma_f32_16x16x32_bf16(ah, bh[j], acc[j], 0, 0, 0);
          acc[j] = __builtin_amdgcn_mfma_f32_16x16x32_bf16(ah, bl[j], acc[j], 0, 0, 0);
          acc[j] = __builtin_amdgcn_mfma_f32_16x16x32_bf16(al, bh[j], acc[j], 0, 0, 0);
        }
        if (kt + 1 < 8) {
          waitvm0();
          if (t < 256) dsw16(ldsaddr(&smem[nxt + dA]), va);
        }
        __syncthreads();
      }
#pragma unroll
      for (int j = 0; j < 4; ++j) {
        const int n = n0 + wn * 64 + j * 16 + c16;
        const int mb = m0 + wm * 16 + q * 4;
        const float bv = bdec[n];
#pragma unroll
        for (int r = 0; r < 4; ++r) {
          const int m = mb + r;
          const size_t idx = (size_t)m * 4096 + n;
          const float cv = canvas[idx] + acc[j][r] + bv;
          canvas[idx] = cv;
          CSTOREU(ehi + (size_t)m * KENC + n, f2b(x[idx] - sigm(cv)));
        }
      }
    }
    if (s + 1 < STEPS) gridbar(bar, ++barid);
  }
}

// ---------------------------------------------------------------------------
extern "C" void kernel_launch(void* const* d_in, const int* in_sizes, int n_in,
                              void* d_out, int out_size, void* d_ws, size_t ws_size,
                              hipStream_t stream) {
  const float* x     = (const float*)d_in[0];
  const float* ek    = (const float*)d_in[1];   // [9728,1024]
  const float* er    = (const float*)d_in[2];   // [256,1024]
  const float* ebias = (const float*)d_in[3];
  const float* dk    = (const float*)d_in[4];   // [256,1024]
  const float* dr    = (const float*)d_in[5];   // [256,1024]
  const float* dbias = (const float*)d_in[6];
  const float* Wenc  = (const float*)d_in[7];   // [256,10]
  const float* benc  = (const float*)d_in[8];
  const float* Wdec  = (const float*)d_in[9];   // [256,4096]
  const float* bdec  = (const float*)d_in[10];

  float* canvas = (float*)d_out;                // [512, 4096] — persistent canvas

  char* p = (char*)d_ws;
  float* c_enc  = (float*)p;        p += (size_t)BSZ * UNITS * 4;
  float* c_dec  = (float*)p;        p += (size_t)BSZ * UNITS * 4;
  float* zep    = (float*)p;        p += (size_t)4 * BSZ * GATES * 4;   // [row][unit][16]
  ushort_t* ehi = (ushort_t*)p;     p += (size_t)BSZ * KENC * 2;
  ushort_t* dhi = (ushort_t*)p;     p += (size_t)BSZ * 512 * 2;
  ushort_t* dlo = (ushort_t*)p;     p += (size_t)BSZ * 512 * 2;
  ushort_t* Wet_hi = (ushort_t*)p;  p += (size_t)GATES * KENC * 2;      // [1024][4608]
  ushort_t* Wdt_hi = (ushort_t*)p;  p += (size_t)GATES * 512 * 2;       // [1024][512]
  ushort_t* Wdt_lo = (ushort_t*)p;  p += (size_t)GATES * 512 * 2;
  ushort_t* Wct_hi = (ushort_t*)p;  p += (size_t)4096 * UNITS * 2;      // [4096][256]
  ushort_t* Wct_lo = (ushort_t*)p;  p += (size_t)4096 * UNITS * 2;
  unsigned* bar = (unsigned*)p;     p += (size_t)(NBLK * FLAG_STRIDE + 16) * 4;

  // ---- weight prep (once per launch) ----
  k_prep_pix<<<dim3(64, 16), 256, 0, stream>>>(ek, Wet_hi);
  k_prep_multi<<<dim3(4, 16, 8), 256, 0, stream>>>(ek, er, dk, dr, Wdec,
                                                   Wet_hi, Wdt_hi, Wdt_lo,
                                                   Wct_hi, Wct_lo, bar);

  // ---- persistent 10-step kernel (cooperative; fallback to plain launch) ----
  void* args[] = {(void*)&x, (void*)&ebias, (void*)&dbias, (void*)&Wenc,
                  (void*)&benc, (void*)&bdec, (void*)&canvas, (void*)&c_enc,
                  (void*)&c_dec, (void*)&zep, (void*)&ehi,
                  (void*)&dhi, (void*)&dlo, (void*)&Wet_hi, (void*)&Wdt_hi,
                  (void*)&Wdt_lo, (void*)&Wct_hi, (void*)&Wct_lo, (void*)&bar};
  if (hipLaunchCooperativeKernel((void*)k_persist, dim3(NBLK), dim3(512),
                                 args, 0, stream) != hipSuccess) {
    k_persist<<<dim3(NBLK), dim3(512), 0, stream>>>(
        x, ebias, dbias, Wenc, benc, bdec, canvas, c_enc, c_dec, zep,
        ehi, dhi, dlo, Wet_hi, Wdt_hi, Wdt_lo, Wct_hi, Wct_lo, bar);
  }
}